// Round 15
// baseline (267.717 us; speedup 1.0000x reference)
//
#include <hip/hip_runtime.h>
#include <cstdint>
#include <cstddef>

typedef short bf16x8 __attribute__((ext_vector_type(8)));
typedef unsigned short u16x4 __attribute__((ext_vector_type(4)));
typedef float f32x4  __attribute__((ext_vector_type(4)));
typedef unsigned short u16;

#define DEVI __device__ __forceinline__

constexpr int C     = 192;
constexpr int HEADS = 6;
constexpr int NQKV  = 576;   // 3*C
constexpr int HID   = 384;   // 2*C
constexpr int NTOK  = 131072;

DEVI u16 f2bf(float f){
  union { float f; unsigned u; } v; v.f = f;
  return (u16)((v.u + 0x7fffu + ((v.u >> 16) & 1u)) >> 16);
}
DEVI float bf2f(u16 h){
  union { unsigned u; float f; } v; v.u = ((unsigned)h) << 16;
  return v.f;
}
// pack two f32 -> two bf16 in one dword (lo = a, hi = b), RNE
DEVI unsigned cvtpk(float a, float b){
  unsigned r;
  asm("v_cvt_pk_bf16_f32 %0, %1, %2" : "=v"(r) : "v"(a), "v"(b));
  return r;
}

// sigmoid-GELU: x * sigma(1.702x); propagated output err ~0.002 after FC2 (headroom 0.08)
DEVI float gelu(float x){
  const float e = __expf(-1.702f * x);
  const float r = __builtin_amdgcn_rcpf(1.f + e);
  return x * r;
}

// ---------------- prep: fragment-packed weights + packed bias table (SWAPPED layout) ----------------
__global__ void prep_kernel(const float* __restrict__ qkv_w,
                            const float* __restrict__ fc1_w,
                            const float* __restrict__ fc2_w,
                            const int*   __restrict__ rpi,
                            const float* __restrict__ rpb,
                            u16* __restrict__ qkvP,
                            u16* __restrict__ fc1P,
                            u16* __restrict__ fc2P,
                            float* __restrict__ bias_pk){
  int idx = blockIdx.x * blockDim.x + threadIdx.x;
  int stride = gridDim.x * blockDim.x;
  for(int i = idx; i < 36*6*64*8; i += stride){
    int e = i & 7, lane = (i >> 3) & 63, t = i >> 9;
    int ks = t % 6, p = t / 6;
    int n = p*16 + (lane & 15), k = ks*32 + (lane >> 4)*8 + e;
    qkvP[i] = f2bf(qkv_w[k*NQKV + n]);
  }
  for(int i = idx; i < 24*6*64*8; i += stride){
    int e = i & 7, lane = (i >> 3) & 63, t = i >> 9;
    int ks = t % 6, p = t / 6;
    int n = p*16 + (lane & 15), k = ks*32 + (lane >> 4)*8 + e;
    fc1P[i] = f2bf(fc1_w[k*HID + n]);
  }
  for(int i = idx; i < 12*12*64*8; i += stride){
    int e = i & 7, lane = (i >> 3) & 63, t = i >> 9;
    int ks = t % 12, p = t / 12;
    int n = p*16 + (lane & 15), k = ks*32 + (lane >> 4)*8 + e;
    fc2P[i] = f2bf(fc2_w[k*C + n]);
  }
  // bias_pk (swapped-QK layout): [head][chunk5][nf2][mi4][lane64][r4]
  const int n4 = HEADS*5*2*4*64*4;
  for(int i = idx; i < n4; i += stride){
    int t = i;
    int r    = t & 3;  t >>= 2;
    int lane = t & 63; t >>= 6;
    int mi   = t & 3;  t >>= 2;
    int nf   = t & 1;  t >>= 1;
    int chunk = t % 5; int head = t / 5;
    int q  = mi*16 + (lane & 15);
    int kk = chunk*32 + nf*16 + ((lane >> 4) << 2) + r;
    float v = 0.f;
    if(kk < 144) v = rpb[rpi[q*144 + kk]*HEADS + head];
    bias_pk[i] = v;
  }
}

// ---------------- LN1 + QKV GEMM -> head-planar qkv bf16 [18 planes][131072][32] ----------------
__global__ __launch_bounds__(384, 4)
void qkv_kernel(const float* __restrict__ x,
                const float* __restrict__ g1,
                const float* __restrict__ b1,
                const u16* __restrict__ wP,
                const float* __restrict__ qb,
                u16* __restrict__ qkv){
  __shared__ u16 xn[64][200];
  __shared__ u16 rp[64][152];
  const int tid = threadIdx.x;
  const int bid = blockIdx.x;
  const int nh = (bid >> 3) & 1;
  const int tb = (bid & 7) + ((bid >> 4) << 3);
  const size_t tok0 = (size_t)tb * 64;
  if(tid < 256){
    const int trow = tid >> 2;
    const int j = tid & 3;
    const float* xr = x + (tok0 + trow)*C;
    float4 xv[12];
    #pragma unroll
    for(int u = 0; u < 12; ++u)
      xv[u] = *reinterpret_cast<const float4*>(xr + u*16 + j*4);
    float s1 = 0.f, s2 = 0.f;
    #pragma unroll
    for(int u = 0; u < 12; ++u){
      const float* f = reinterpret_cast<const float*>(&xv[u]);
      #pragma unroll
      for(int e = 0; e < 4; ++e){ s1 += f[e]; s2 += f[e]*f[e]; }
    }
    s1 += __shfl_xor(s1, 1, 64); s2 += __shfl_xor(s2, 1, 64);
    s1 += __shfl_xor(s1, 2, 64); s2 += __shfl_xor(s2, 2, 64);
    const float mean = s1 * (1.f/192.f);
    const float rstd = rsqrtf(s2*(1.f/192.f) - mean*mean + 1e-5f);
    #pragma unroll
    for(int u = 0; u < 12; ++u){
      const float4 gv = *reinterpret_cast<const float4*>(g1 + u*16 + j*4);
      const float4 bv = *reinterpret_cast<const float4*>(b1 + u*16 + j*4);
      const float* f = reinterpret_cast<const float*>(&xv[u]);
      const float* gp = reinterpret_cast<const float*>(&gv);
      const float* bp = reinterpret_cast<const float*>(&bv);
      float c0 = (f[0] - mean)*rstd*gp[0] + bp[0];
      float c1 = (f[1] - mean)*rstd*gp[1] + bp[1];
      float c2 = (f[2] - mean)*rstd*gp[2] + bp[2];
      float c3 = (f[3] - mean)*rstd*gp[3] + bp[3];
      uint2 pk; pk.x = cvtpk(c0, c1); pk.y = cvtpk(c2, c3);
      *reinterpret_cast<uint2*>(&xn[trow][u*16 + j*4]) = pk;
    }
  }
  __syncthreads();
  const int lane = tid & 63;
  const int wn = tid >> 6;
  const int g = lane >> 4, col = lane & 15;
  const f32x4 fzero = {0.f, 0.f, 0.f, 0.f};
  f32x4 acc[4][3];
  #pragma unroll
  for(int mi = 0; mi < 4; ++mi)
    #pragma unroll
    for(int nf = 0; nf < 3; ++nf) acc[mi][nf] = fzero;
  const int p0 = nh*18 + wn*3;
  #pragma unroll
  for(int ks = 0; ks < 6; ++ks){
    bf16x8 wf[3];
    #pragma unroll
    for(int nf = 0; nf < 3; ++nf)
      wf[nf] = *reinterpret_cast<const bf16x8*>(wP + ((size_t)(((p0 + nf)*6 + ks)*64) + lane)*8);
    bf16x8 a[4];
    #pragma unroll
    for(int mi = 0; mi < 4; ++mi)
      a[mi] = *reinterpret_cast<const bf16x8*>(&xn[mi*16 + col][ks*32 + g*8]);
    #pragma unroll
    for(int nf = 0; nf < 3; ++nf)
      #pragma unroll
      for(int mi = 0; mi < 4; ++mi)
        acc[mi][nf] = __builtin_amdgcn_mfma_f32_16x16x32_bf16(a[mi], wf[nf], acc[mi][nf], 0, 0, 0);
  }
  #pragma unroll
  for(int ph = 0; ph < 2; ++ph){
    if(wn >= ph*3 && wn < ph*3 + 3){
      const int wl = wn - ph*3;
      #pragma unroll
      for(int mi = 0; mi < 4; ++mi){
        #pragma unroll
        for(int nf = 0; nf < 3; ++nf){
          const int nloc = wl*48 + nf*16 + col;
          const float bb = qb[nh*288 + ph*144 + nloc];
          const int row0 = mi*16 + g*4;
          const unsigned p01 = cvtpk(acc[mi][nf][0] + bb, acc[mi][nf][1] + bb);
          const unsigned p23 = cvtpk(acc[mi][nf][2] + bb, acc[mi][nf][3] + bb);
          rp[row0 + 0][nloc] = (u16)p01;
          rp[row0 + 1][nloc] = (u16)(p01 >> 16);
          rp[row0 + 2][nloc] = (u16)p23;
          rp[row0 + 3][nloc] = (u16)(p23 >> 16);
        }
      }
    }
    __syncthreads();
    #pragma unroll
    for(int it = 0; it < 3; ++it){
      const int c = tid + it*384;
      const int tok = c / 18, cc = c - tok*18;
      const int n0 = nh*288 + ph*144 + cc*8;
      const int pl = n0 >> 5, d0 = n0 & 31;
      bf16x8 vv = *reinterpret_cast<const bf16x8*>(&rp[tok][cc*8]);
      *reinterpret_cast<bf16x8*>(qkv + ((size_t)pl*NTOK + tok0 + tok)*32 + d0) = vv;
    }
    __syncthreads();
  }
}

// ---------------- windowed attention: per (window, head), 4 waves; ping-pong P buffer ----------------
// X1B=true: write x1 = O + x as bf16 to x1b. X1B=false: write f32 to out.
template<bool X1B>
__global__ __launch_bounds__(256, 4)
void attn_kernel(const u16* __restrict__ qkv,   // [18][131072][32]
                 const float* __restrict__ bias_pk,
                 const float* __restrict__ x,
                 float* __restrict__ out,
                 u16* __restrict__ x1b){
  __shared__ alignas(16) char smem[33792];
  u16 (*Kl)[40]  = reinterpret_cast<u16(*)[40]>(smem);            // 160 x 80B = 12800
  u16 (*Vt)[168] = reinterpret_cast<u16(*)[168]>(smem + 12800);   // 32 x 336B = 10752
  char* Plb      = smem + 23552;                                  // 2 x (64 x 80B) = 10240 (ping-pong)
  float (*Of)[36] = reinterpret_cast<float(*)[36]>(smem);         // aliases Kl (after barrier)
  const int tid  = threadIdx.x;
  const int lane = tid & 63;
  const int w    = tid >> 6;    // wave id = q-tile
  const int g = lane >> 4, col = lane & 15;
  const int win = blockIdx.x, head = blockIdx.y;
  const int bt = win >> 8, wh = (win >> 4) & 15, ww = win & 15;
  const int h0 = wh*8, w0 = ww*8;
  const size_t tokbase = (size_t)bt * 16384;
  const u16* Qp = qkv + (size_t)head      *NTOK*32;
  const u16* Kp = qkv + (size_t)(6 + head)*NTOK*32;
  const u16* Vp = qkv + (size_t)(12 + head)*NTOK*32;
  const bf16x8 z8 = {0,0,0,0,0,0,0,0};

  // ---- staging: waves split the 10 row-groups ----
  #pragma unroll
  for(int ii = 0; ii < 3; ++ii){
    const int i = w + ii*4;
    if(i < 10){
      const int kr = i*16 + col;
      const int r12 = (kr*2731) >> 15;       // kr/12
      const int c12 = kr - r12*12;
      const int hh = h0 - 2 + r12;
      const int wp = w0 - 2 + c12;
      const bool valid = (kr < 144) && (hh >= 0) && (hh < 128) && (wp >= 0) && (wp < 128);
      const size_t t = valid ? (tokbase + (size_t)hh*128 + wp) : tokbase;
      bf16x8 kv_ = *reinterpret_cast<const bf16x8*>(Kp + t*32 + g*8);
      bf16x8 vv_ = *reinterpret_cast<const bf16x8*>(Vp + t*32 + g*8);
      kv_ = valid ? kv_ : z8;
      vv_ = valid ? vv_ : z8;
      *reinterpret_cast<bf16x8*>(&Kl[kr][g*8]) = kv_;
      #pragma unroll
      for(int e = 0; e < 8; ++e) Vt[g*8 + e][kr] = (u16)vv_[e];
    }
  }
  bf16x8 qf;
  {
    const int row = w*16 + col;
    const size_t t = tokbase + (size_t)(h0 + (row >> 3))*128 + (w0 + (row & 7));
    qf = *reinterpret_cast<const bf16x8*>(Qp + t*32 + g*8);
  }
  __syncthreads();

  const f32x4 fzero = {0.f, 0.f, 0.f, 0.f};
  f32x4 oacc[2];
  oacc[0] = fzero; oacc[1] = fzero;
  const float scale = 0.17677669529663689f;  // 32^-0.5

  #pragma unroll
  for(int ch = 0; ch < 5; ++ch){
    char* pch = Plb + (ch & 1)*5120;   // ping-pong: breaks cross-chunk WAR on P buffer
    float4 bv[2];
    #pragma unroll
    for(int nf = 0; nf < 2; ++nf)
      bv[nf] = *reinterpret_cast<const float4*>(
          bias_pk + (size_t)((((head*5 + ch)*2 + nf)*4 + w)*64 + lane)*4);
    bf16x8 kfr[2];
    #pragma unroll
    for(int nf = 0; nf < 2; ++nf)
      kfr[nf] = *reinterpret_cast<const bf16x8*>(&Kl[ch*32 + nf*16 + col][g*8]);
    f32x4 st[2];
    #pragma unroll
    for(int nf = 0; nf < 2; ++nf)
      st[nf] = __builtin_amdgcn_mfma_f32_16x16x32_bf16(kfr[nf], qf, fzero, 0, 0, 0);
    #pragma unroll
    for(int nf = 0; nf < 2; ++nf){
      const float* bp = reinterpret_cast<const float*>(&bv[nf]);
      const float p0 = fmaf(st[nf][0], scale, bp[0]);
      const float p1 = fmaf(st[nf][1], scale, bp[1]);
      const float p2 = fmaf(st[nf][2], scale, bp[2]);
      const float p3 = fmaf(st[nf][3], scale, bp[3]);
      uint2 pw;
      pw.x = cvtpk(p0, p1);
      pw.y = cvtpk(p2, p3);
      *reinterpret_cast<uint2*>(pch + (w*16 + col)*80 + nf*32 + g*8) = pw;
    }
    bf16x8 pa = *reinterpret_cast<const bf16x8*>(pch + (w*16 + col)*80 + g*16);
    bf16x8 vfr[2];
    #pragma unroll
    for(int nf = 0; nf < 2; ++nf)
      vfr[nf] = *reinterpret_cast<const bf16x8*>(&Vt[nf*16 + col][ch*32 + g*8]);
    #pragma unroll
    for(int nf = 0; nf < 2; ++nf)
      oacc[nf] = __builtin_amdgcn_mfma_f32_16x16x32_bf16(pa, vfr[nf], oacc[nf], 0, 0, 0);
  }
  __syncthreads();   // all Kl reads done; safe to alias with Of
  #pragma unroll
  for(int nf = 0; nf < 2; ++nf)
    #pragma unroll
    for(int r = 0; r < 4; ++r)
      Of[w*16 + g*4 + r][nf*16 + col] = oacc[nf][r];
  __syncthreads();
  // epilogue: x1 = O + shortcut
  {
    const int tok = tid >> 2, q = tid & 3;
    const int hh = h0 + (tok >> 3), wp = w0 + (tok & 7);
    const size_t trow = tokbase + (size_t)hh*128 + wp;
    const size_t o = trow*(size_t)C + head*32 + q*8;
    float4 a0 = *reinterpret_cast<const float4*>(&Of[tok][q*8]);
    float4 a1 = *reinterpret_cast<const float4*>(&Of[tok][q*8 + 4]);
    const float4 x0 = *reinterpret_cast<const float4*>(x + o);
    const float4 x1 = *reinterpret_cast<const float4*>(x + o + 4);
    a0.x += x0.x; a0.y += x0.y; a0.z += x0.z; a0.w += x0.w;
    a1.x += x1.x; a1.y += x1.y; a1.z += x1.z; a1.w += x1.w;
    if(X1B){
      uint4 pk;
      pk.x = cvtpk(a0.x, a0.y);
      pk.y = cvtpk(a0.z, a0.w);
      pk.z = cvtpk(a1.x, a1.y);
      pk.w = cvtpk(a1.z, a1.w);
      *reinterpret_cast<uint4*>(x1b + o) = pk;
    }else{
      *reinterpret_cast<float4*>(out + o)     = a0;
      *reinterpret_cast<float4*>(out + o + 4) = a1;
    }
  }
}

// ---------------- LN2 + FC1 + GELU + FC2 + residual ----------------
// 32 tokens/block, 4096 blocks, 4 waves; single FC1->FC2 pass, 37KB LDS -> 4 blocks/CU.
template<bool X1B>
__global__ __launch_bounds__(256, 4)
void mlp_kernel(float* __restrict__ io,            // X1B ? out (write-only) : in-place x1/out
                const u16* __restrict__ x1b,       // X1B only
                const float* __restrict__ g2,
                const float* __restrict__ b2,
                const u16* __restrict__ w1P,
                const float* __restrict__ fb1,
                const u16* __restrict__ w2P,
                const float* __restrict__ fb2){
  __shared__ u16 xn[32][200];
  __shared__ u16 hl[32][392];
  const int tid = threadIdx.x;
  const size_t tok0 = (size_t)blockIdx.x * 32;
  {
    const int trow = tid >> 3;   // 0..31
    const int j = tid & 7;       // 24 floats each
    float v[24];
    if(X1B){
      const u16* xr = x1b + (tok0 + trow)*C + j*24;
      bf16x8 b0 = *reinterpret_cast<const bf16x8*>(xr);
      bf16x8 b1 = *reinterpret_cast<const bf16x8*>(xr + 8);
      bf16x8 b2_ = *reinterpret_cast<const bf16x8*>(xr + 16);
      #pragma unroll
      for(int e = 0; e < 8; ++e){ v[e] = bf2f((u16)b0[e]); v[8+e] = bf2f((u16)b1[e]); v[16+e] = bf2f((u16)b2_[e]); }
    }else{
      const float* xr = io + (tok0 + trow)*C + j*24;
      #pragma unroll
      for(int u = 0; u < 6; ++u){
        const float4 t = *reinterpret_cast<const float4*>(xr + u*4);
        v[u*4+0] = t.x; v[u*4+1] = t.y; v[u*4+2] = t.z; v[u*4+3] = t.w;
      }
    }
    float s1 = 0.f, s2 = 0.f;
    #pragma unroll
    for(int e = 0; e < 24; ++e){ s1 += v[e]; s2 += v[e]*v[e]; }
    s1 += __shfl_xor(s1, 1, 64); s2 += __shfl_xor(s2, 1, 64);
    s1 += __shfl_xor(s1, 2, 64); s2 += __shfl_xor(s2, 2, 64);
    s1 += __shfl_xor(s1, 4, 64); s2 += __shfl_xor(s2, 4, 64);
    const float mean = s1 * (1.f/192.f);
    const float rstd = rsqrtf(s2*(1.f/192.f) - mean*mean + 1e-5f);
    #pragma unroll
    for(int u = 0; u < 6; ++u){
      const float4 gv = *reinterpret_cast<const float4*>(g2 + j*24 + u*4);
      const float4 bv = *reinterpret_cast<const float4*>(b2 + j*24 + u*4);
      const float* gp = reinterpret_cast<const float*>(&gv);
      const float* bp = reinterpret_cast<const float*>(&bv);
      float c0 = (v[u*4+0] - mean)*rstd*gp[0] + bp[0];
      float c1 = (v[u*4+1] - mean)*rstd*gp[1] + bp[1];
      float c2 = (v[u*4+2] - mean)*rstd*gp[2] + bp[2];
      float c3 = (v[u*4+3] - mean)*rstd*gp[3] + bp[3];
      uint2 pk; pk.x = cvtpk(c0, c1); pk.y = cvtpk(c2, c3);
      *reinterpret_cast<uint2*>(&xn[trow][j*24 + u*4]) = pk;
    }
  }
  __syncthreads();
  const int lane = tid & 63, w = tid >> 6;   // w = 0..3
  const int g = lane >> 4, col = lane & 15;
  const f32x4 fzero = {0.f, 0.f, 0.f, 0.f};
  // ---- FC1: wave w -> hid cols [w*96, w*96+96) over all 32 rows; acc1[2][6] ----
  f32x4 acc1[2][6];
  #pragma unroll
  for(int mi = 0; mi < 2; ++mi)
    #pragma unroll
    for(int nf = 0; nf < 6; ++nf) acc1[mi][nf] = fzero;
  #pragma unroll
  for(int ks = 0; ks < 6; ++ks){
    bf16x8 wf[6];
    #pragma unroll
    for(int nf = 0; nf < 6; ++nf)
      wf[nf] = *reinterpret_cast<const bf16x8*>(w1P + ((size_t)(((w*6 + nf)*6 + ks)*64) + lane)*8);
    bf16x8 a[2];
    #pragma unroll
    for(int mi = 0; mi < 2; ++mi)
      a[mi] = *reinterpret_cast<const bf16x8*>(&xn[mi*16 + col][ks*32 + g*8]);
    #pragma unroll
    for(int nf = 0; nf < 6; ++nf)
      #pragma unroll
      for(int mi = 0; mi < 2; ++mi)
        acc1[mi][nf] = __builtin_amdgcn_mfma_f32_16x16x32_bf16(a[mi], wf[nf], acc1[mi][nf], 0, 0, 0);
  }
  // bias + gelu -> hl (consecutive-row pairs via cvt_pk)
  #pragma unroll
  for(int mi = 0; mi < 2; ++mi){
    #pragma unroll
    for(int nf = 0; nf < 6; ++nf){
      const int nl = w*96 + nf*16 + col;
      const float bb = fb1[nl];
      const int row0 = mi*16 + g*4;
      const unsigned p01 = cvtpk(gelu(acc1[mi][nf][0] + bb), gelu(acc1[mi][nf][1] + bb));
      const unsigned p23 = cvtpk(gelu(acc1[mi][nf][2] + bb), gelu(acc1[mi][nf][3] + bb));
      hl[row0 + 0][nl] = (u16)p01;
      hl[row0 + 1][nl] = (u16)(p01 >> 16);
      hl[row0 + 2][nl] = (u16)p23;
      hl[row0 + 3][nl] = (u16)(p23 >> 16);
    }
  }
  __syncthreads();   // hl ready; xn reads done
  // ---- FC2: wave w -> out cols [w*48, w*48+48) over all 32 rows; acc2[2][3], k = 384 ----
  f32x4 acc2[2][3];
  #pragma unroll
  for(int mi = 0; mi < 2; ++mi)
    #pragma unroll
    for(int nf = 0; nf < 3; ++nf) acc2[mi][nf] = fzero;
  #pragma unroll
  for(int ks = 0; ks < 12; ++ks){
    bf16x8 wf[3];
    #pragma unroll
    for(int nf = 0; nf < 3; ++nf)
      wf[nf] = *reinterpret_cast<const bf16x8*>(w2P + ((size_t)(((w*3 + nf)*12 + ks)*64) + lane)*8);
    bf16x8 a[2];
    #pragma unroll
    for(int mi = 0; mi < 2; ++mi)
      a[mi] = *reinterpret_cast<const bf16x8*>(&hl[mi*16 + col][ks*32 + g*8]);
    #pragma unroll
    for(int nf = 0; nf < 3; ++nf)
      #pragma unroll
      for(int mi = 0; mi < 2; ++mi)
        acc2[mi][nf] = __builtin_amdgcn_mfma_f32_16x16x32_bf16(a[mi], wf[nf], acc2[mi][nf], 0, 0, 0);
  }
  if(X1B){
    // stage mlp-out bf16 into xn (free after FC1), then pure vector write of x1 + mlp-out
    #pragma unroll
    for(int mi = 0; mi < 2; ++mi){
      #pragma unroll
      for(int nf = 0; nf < 3; ++nf){
        const int n = w*48 + nf*16 + col;
        const float bb = fb2[n];
        const int row0 = mi*16 + g*4;
        const unsigned p01 = cvtpk(acc2[mi][nf][0] + bb, acc2[mi][nf][1] + bb);
        const unsigned p23 = cvtpk(acc2[mi][nf][2] + bb, acc2[mi][nf][3] + bb);
        xn[row0 + 0][n] = (u16)p01;
        xn[row0 + 1][n] = (u16)(p01 >> 16);
        xn[row0 + 2][n] = (u16)p23;
        xn[row0 + 3][n] = (u16)(p23 >> 16);
      }
    }
    __syncthreads();
    const int trow = tid >> 3, j = tid & 7;
    const u16* xq = x1b + (tok0 + trow)*C + j*24;   // L2-hit (read by this block in LN)
    float* op = io + (tok0 + trow)*C + j*24;
    bf16x8 r0 = *reinterpret_cast<const bf16x8*>(xq);
    bf16x8 r1 = *reinterpret_cast<const bf16x8*>(xq + 8);
    bf16x8 r2 = *reinterpret_cast<const bf16x8*>(xq + 16);
    bf16x8 m0 = *reinterpret_cast<const bf16x8*>(&xn[trow][j*24]);
    bf16x8 m1 = *reinterpret_cast<const bf16x8*>(&xn[trow][j*24 + 8]);
    bf16x8 m2 = *reinterpret_cast<const bf16x8*>(&xn[trow][j*24 + 16]);
    float ov[24];
    #pragma unroll
    for(int e = 0; e < 8; ++e){
      ov[e]    = bf2f((u16)r0[e]) + bf2f((u16)m0[e]);
      ov[8+e]  = bf2f((u16)r1[e]) + bf2f((u16)m1[e]);
      ov[16+e] = bf2f((u16)r2[e]) + bf2f((u16)m2[e]);
    }
    #pragma unroll
    for(int u = 0; u < 6; ++u){
      float4 t; t.x = ov[u*4]; t.y = ov[u*4+1]; t.z = ov[u*4+2]; t.w = ov[u*4+3];
      *reinterpret_cast<float4*>(op + u*4) = t;
    }
  }else{
    // in-place scalar RMW
    #pragma unroll
    for(int mi = 0; mi < 2; ++mi){
      #pragma unroll
      for(int nf = 0; nf < 3; ++nf){
        const int n = w*48 + nf*16 + col;
        const float bb = fb2[n];
        #pragma unroll
        for(int r = 0; r < 4; ++r){
          const int row = mi*16 + g*4 + r;
          const size_t idx = (tok0 + row)*C + n;
          io[idx] = acc2[mi][nf][r] + bb + io[idx];
        }
      }
    }
  }
}

extern "C" void kernel_launch(void* const* d_in, const int* in_sizes, int n_in,
                              void* d_out, int out_size, void* d_ws, size_t ws_size,
                              hipStream_t stream){
  const float* x    = (const float*)d_in[0];
  const int*   rpi  = (const int*)  d_in[2];
  const float* n1g  = (const float*)d_in[3];
  const float* n1b  = (const float*)d_in[4];
  const float* qkvw = (const float*)d_in[5];
  const float* qkvb = (const float*)d_in[6];
  const float* rpb  = (const float*)d_in[7];
  const float* n2g  = (const float*)d_in[8];
  const float* n2b  = (const float*)d_in[9];
  const float* fc1w = (const float*)d_in[10];
  const float* fc1b = (const float*)d_in[11];
  const float* fc2w = (const float*)d_in[12];
  const float* fc2b = (const float*)d_in[13];
  float* out = (float*)d_out;
  char* ws = (char*)d_ws;
  u16*   qkvP    = (u16*)  (ws + 0);
  u16*   fc1P    = (u16*)  (ws + 221184);
  u16*   fc2P    = (u16*)  (ws + 368640);
  float* bias_pk = (float*)(ws + 516096);
  u16*   qkvbuf  = (u16*)  (ws + 1499136);       // 150994944 B
  u16*   x1b     = (u16*)  (ws + 152494080);     // 50331648 B (big-ws path only)
  if(ws_size < 152494080ull) return;
  const bool big = ws_size >= 202825728ull;
  prep_kernel<<<dim3(512), dim3(256), 0, stream>>>(qkvw, fc1w, fc2w, rpi, rpb, qkvP, fc1P, fc2P, bias_pk);
  qkv_kernel<<<dim3(4096), dim3(384), 0, stream>>>(x, n1g, n1b, qkvP, qkvb, qkvbuf);
  if(big){
    attn_kernel<true><<<dim3(2048, 6), dim3(256), 0, stream>>>(qkvbuf, bias_pk, x, out, x1b);
    mlp_kernel<true><<<dim3(4096), dim3(256), 0, stream>>>(out, x1b, n2g, n2b, fc1P, fc1b, fc2P, fc2b);
  }else{
    attn_kernel<false><<<dim3(2048, 6), dim3(256), 0, stream>>>(qkvbuf, bias_pk, x, out, nullptr);
    mlp_kernel<false><<<dim3(4096), dim3(256), 0, stream>>>(out, nullptr, n2g, n2b, fc1P, fc1b, fc2P, fc2b);
  }
}

// Round 16
// 261.287 us; speedup vs baseline: 1.0246x; 1.0246x over previous
//
#include <hip/hip_runtime.h>
#include <cstdint>
#include <cstddef>

typedef short bf16x8 __attribute__((ext_vector_type(8)));
typedef unsigned short u16x4 __attribute__((ext_vector_type(4)));
typedef float f32x4  __attribute__((ext_vector_type(4)));
typedef unsigned short u16;

#define DEVI __device__ __forceinline__

constexpr int C     = 192;
constexpr int HEADS = 6;
constexpr int NQKV  = 576;   // 3*C
constexpr int HID   = 384;   // 2*C
constexpr int NTOK  = 131072;

DEVI u16 f2bf(float f){
  union { float f; unsigned u; } v; v.f = f;
  return (u16)((v.u + 0x7fffu + ((v.u >> 16) & 1u)) >> 16);
}
DEVI float bf2f(u16 h){
  union { unsigned u; float f; } v; v.u = ((unsigned)h) << 16;
  return v.f;
}
// pack two f32 -> two bf16 in one dword (lo = a, hi = b), RNE
DEVI unsigned cvtpk(float a, float b){
  unsigned r;
  asm("v_cvt_pk_bf16_f32 %0, %1, %2" : "=v"(r) : "v"(a), "v"(b));
  return r;
}

// sigmoid-GELU: x * sigma(1.702x); propagated output err ~0.002 after FC2
DEVI float gelu(float x){
  const float e = __expf(-1.702f * x);
  const float r = __builtin_amdgcn_rcpf(1.f + e);
  return x * r;
}

// ---------------- prep: fragment-packed weights + packed bias table (SWAPPED layout) ----------------
__global__ void prep_kernel(const float* __restrict__ qkv_w,
                            const float* __restrict__ fc1_w,
                            const float* __restrict__ fc2_w,
                            const int*   __restrict__ rpi,
                            const float* __restrict__ rpb,
                            u16* __restrict__ qkvP,
                            u16* __restrict__ fc1P,
                            u16* __restrict__ fc2P,
                            float* __restrict__ bias_pk){
  int idx = blockIdx.x * blockDim.x + threadIdx.x;
  int stride = gridDim.x * blockDim.x;
  for(int i = idx; i < 36*6*64*8; i += stride){
    int e = i & 7, lane = (i >> 3) & 63, t = i >> 9;
    int ks = t % 6, p = t / 6;
    int n = p*16 + (lane & 15), k = ks*32 + (lane >> 4)*8 + e;
    qkvP[i] = f2bf(qkv_w[k*NQKV + n]);
  }
  for(int i = idx; i < 24*6*64*8; i += stride){
    int e = i & 7, lane = (i >> 3) & 63, t = i >> 9;
    int ks = t % 6, p = t / 6;
    int n = p*16 + (lane & 15), k = ks*32 + (lane >> 4)*8 + e;
    fc1P[i] = f2bf(fc1_w[k*HID + n]);
  }
  for(int i = idx; i < 12*12*64*8; i += stride){
    int e = i & 7, lane = (i >> 3) & 63, t = i >> 9;
    int ks = t % 12, p = t / 12;
    int n = p*16 + (lane & 15), k = ks*32 + (lane >> 4)*8 + e;
    fc2P[i] = f2bf(fc2_w[k*C + n]);
  }
  // bias_pk (swapped-QK layout): [head][chunk5][nf2][mi4][lane64][r4]
  const int n4 = HEADS*5*2*4*64*4;
  for(int i = idx; i < n4; i += stride){
    int t = i;
    int r    = t & 3;  t >>= 2;
    int lane = t & 63; t >>= 6;
    int mi   = t & 3;  t >>= 2;
    int nf   = t & 1;  t >>= 1;
    int chunk = t % 5; int head = t / 5;
    int q  = mi*16 + (lane & 15);
    int kk = chunk*32 + nf*16 + ((lane >> 4) << 2) + r;
    float v = 0.f;
    if(kk < 144) v = rpb[rpi[q*144 + kk]*HEADS + head];
    bias_pk[i] = v;
  }
}

// ---------------- LN1 + QKV GEMM -> head-planar qkv bf16 [18 planes][131072][32] ----------------
__global__ __launch_bounds__(384, 4)
void qkv_kernel(const float* __restrict__ x,
                const float* __restrict__ g1,
                const float* __restrict__ b1,
                const u16* __restrict__ wP,
                const float* __restrict__ qb,
                u16* __restrict__ qkv){
  __shared__ u16 xn[64][200];
  __shared__ u16 rp[64][152];
  const int tid = threadIdx.x;
  const int bid = blockIdx.x;
  const int nh = (bid >> 3) & 1;
  const int tb = (bid & 7) + ((bid >> 4) << 3);
  const size_t tok0 = (size_t)tb * 64;
  if(tid < 256){
    const int trow = tid >> 2;
    const int j = tid & 3;
    const float* xr = x + (tok0 + trow)*C;
    float4 xv[12];
    #pragma unroll
    for(int u = 0; u < 12; ++u)
      xv[u] = *reinterpret_cast<const float4*>(xr + u*16 + j*4);
    float s1 = 0.f, s2 = 0.f;
    #pragma unroll
    for(int u = 0; u < 12; ++u){
      const float* f = reinterpret_cast<const float*>(&xv[u]);
      #pragma unroll
      for(int e = 0; e < 4; ++e){ s1 += f[e]; s2 += f[e]*f[e]; }
    }
    s1 += __shfl_xor(s1, 1, 64); s2 += __shfl_xor(s2, 1, 64);
    s1 += __shfl_xor(s1, 2, 64); s2 += __shfl_xor(s2, 2, 64);
    const float mean = s1 * (1.f/192.f);
    const float rstd = rsqrtf(s2*(1.f/192.f) - mean*mean + 1e-5f);
    #pragma unroll
    for(int u = 0; u < 12; ++u){
      const float4 gv = *reinterpret_cast<const float4*>(g1 + u*16 + j*4);
      const float4 bv = *reinterpret_cast<const float4*>(b1 + u*16 + j*4);
      const float* f = reinterpret_cast<const float*>(&xv[u]);
      const float* gp = reinterpret_cast<const float*>(&gv);
      const float* bp = reinterpret_cast<const float*>(&bv);
      float c0 = (f[0] - mean)*rstd*gp[0] + bp[0];
      float c1 = (f[1] - mean)*rstd*gp[1] + bp[1];
      float c2 = (f[2] - mean)*rstd*gp[2] + bp[2];
      float c3 = (f[3] - mean)*rstd*gp[3] + bp[3];
      uint2 pk; pk.x = cvtpk(c0, c1); pk.y = cvtpk(c2, c3);
      *reinterpret_cast<uint2*>(&xn[trow][u*16 + j*4]) = pk;
    }
  }
  __syncthreads();
  const int lane = tid & 63;
  const int wn = tid >> 6;
  const int g = lane >> 4, col = lane & 15;
  const f32x4 fzero = {0.f, 0.f, 0.f, 0.f};
  f32x4 acc[4][3];
  #pragma unroll
  for(int mi = 0; mi < 4; ++mi)
    #pragma unroll
    for(int nf = 0; nf < 3; ++nf) acc[mi][nf] = fzero;
  const int p0 = nh*18 + wn*3;
  #pragma unroll
  for(int ks = 0; ks < 6; ++ks){
    bf16x8 wf[3];
    #pragma unroll
    for(int nf = 0; nf < 3; ++nf)
      wf[nf] = *reinterpret_cast<const bf16x8*>(wP + ((size_t)(((p0 + nf)*6 + ks)*64) + lane)*8);
    bf16x8 a[4];
    #pragma unroll
    for(int mi = 0; mi < 4; ++mi)
      a[mi] = *reinterpret_cast<const bf16x8*>(&xn[mi*16 + col][ks*32 + g*8]);
    #pragma unroll
    for(int nf = 0; nf < 3; ++nf)
      #pragma unroll
      for(int mi = 0; mi < 4; ++mi)
        acc[mi][nf] = __builtin_amdgcn_mfma_f32_16x16x32_bf16(a[mi], wf[nf], acc[mi][nf], 0, 0, 0);
  }
  #pragma unroll
  for(int ph = 0; ph < 2; ++ph){
    if(wn >= ph*3 && wn < ph*3 + 3){
      const int wl = wn - ph*3;
      #pragma unroll
      for(int mi = 0; mi < 4; ++mi){
        #pragma unroll
        for(int nf = 0; nf < 3; ++nf){
          const int nloc = wl*48 + nf*16 + col;
          const float bb = qb[nh*288 + ph*144 + nloc];
          const int row0 = mi*16 + g*4;
          const unsigned p01 = cvtpk(acc[mi][nf][0] + bb, acc[mi][nf][1] + bb);
          const unsigned p23 = cvtpk(acc[mi][nf][2] + bb, acc[mi][nf][3] + bb);
          rp[row0 + 0][nloc] = (u16)p01;
          rp[row0 + 1][nloc] = (u16)(p01 >> 16);
          rp[row0 + 2][nloc] = (u16)p23;
          rp[row0 + 3][nloc] = (u16)(p23 >> 16);
        }
      }
    }
    __syncthreads();
    #pragma unroll
    for(int it = 0; it < 3; ++it){
      const int c = tid + it*384;
      const int tok = c / 18, cc = c - tok*18;
      const int n0 = nh*288 + ph*144 + cc*8;
      const int pl = n0 >> 5, d0 = n0 & 31;
      bf16x8 vv = *reinterpret_cast<const bf16x8*>(&rp[tok][cc*8]);
      *reinterpret_cast<bf16x8*>(qkv + ((size_t)pl*NTOK + tok0 + tok)*32 + d0) = vv;
    }
    __syncthreads();
  }
}

// ---------------- windowed attention: per (window, head), 4 waves (r14 best config) ----------------
// X1B=true: write x1 = O + x as bf16 to x1b. X1B=false: write f32 to out.
template<bool X1B>
__global__ __launch_bounds__(256, 5)
void attn_kernel(const u16* __restrict__ qkv,   // [18][131072][32]
                 const float* __restrict__ bias_pk,
                 const float* __restrict__ x,
                 float* __restrict__ out,
                 u16* __restrict__ x1b){
  __shared__ alignas(16) char smem[28672];
  u16 (*Kl)[40]  = reinterpret_cast<u16(*)[40]>(smem);            // 160 x 80B = 12800
  u16 (*Vt)[168] = reinterpret_cast<u16(*)[168]>(smem + 12800);   // 32 x 336B = 10752
  char* Plb      = smem + 23552;                                  // 64 x 80B  =  5120
  float (*Of)[36] = reinterpret_cast<float(*)[36]>(smem);         // aliases Kl (after barrier)
  const int tid  = threadIdx.x;
  const int lane = tid & 63;
  const int w    = tid >> 6;    // wave id = q-tile
  const int g = lane >> 4, col = lane & 15;
  const int win = blockIdx.x, head = blockIdx.y;
  const int bt = win >> 8, wh = (win >> 4) & 15, ww = win & 15;
  const int h0 = wh*8, w0 = ww*8;
  const size_t tokbase = (size_t)bt * 16384;
  const u16* Qp = qkv + (size_t)head      *NTOK*32;
  const u16* Kp = qkv + (size_t)(6 + head)*NTOK*32;
  const u16* Vp = qkv + (size_t)(12 + head)*NTOK*32;
  const bf16x8 z8 = {0,0,0,0,0,0,0,0};

  // ---- staging: waves split the 10 row-groups ----
  #pragma unroll
  for(int ii = 0; ii < 3; ++ii){
    const int i = w + ii*4;
    if(i < 10){
      const int kr = i*16 + col;
      const int r12 = (kr*2731) >> 15;       // kr/12
      const int c12 = kr - r12*12;
      const int hh = h0 - 2 + r12;
      const int wp = w0 - 2 + c12;
      const bool valid = (kr < 144) && (hh >= 0) && (hh < 128) && (wp >= 0) && (wp < 128);
      const size_t t = valid ? (tokbase + (size_t)hh*128 + wp) : tokbase;
      bf16x8 kv_ = *reinterpret_cast<const bf16x8*>(Kp + t*32 + g*8);
      bf16x8 vv_ = *reinterpret_cast<const bf16x8*>(Vp + t*32 + g*8);
      kv_ = valid ? kv_ : z8;
      vv_ = valid ? vv_ : z8;
      *reinterpret_cast<bf16x8*>(&Kl[kr][g*8]) = kv_;
      #pragma unroll
      for(int e = 0; e < 8; ++e) Vt[g*8 + e][kr] = (u16)vv_[e];
    }
  }
  bf16x8 qf;
  {
    const int row = w*16 + col;
    const size_t t = tokbase + (size_t)(h0 + (row >> 3))*128 + (w0 + (row & 7));
    qf = *reinterpret_cast<const bf16x8*>(Qp + t*32 + g*8);
  }
  __syncthreads();

  const f32x4 fzero = {0.f, 0.f, 0.f, 0.f};
  f32x4 oacc[2];
  oacc[0] = fzero; oacc[1] = fzero;
  const float scale = 0.17677669529663689f;  // 32^-0.5

  #pragma unroll
  for(int ch = 0; ch < 5; ++ch){
    float4 bv[2];
    #pragma unroll
    for(int nf = 0; nf < 2; ++nf)
      bv[nf] = *reinterpret_cast<const float4*>(
          bias_pk + (size_t)((((head*5 + ch)*2 + nf)*4 + w)*64 + lane)*4);
    bf16x8 kfr[2];
    #pragma unroll
    for(int nf = 0; nf < 2; ++nf)
      kfr[nf] = *reinterpret_cast<const bf16x8*>(&Kl[ch*32 + nf*16 + col][g*8]);
    f32x4 st[2];
    #pragma unroll
    for(int nf = 0; nf < 2; ++nf)
      st[nf] = __builtin_amdgcn_mfma_f32_16x16x32_bf16(kfr[nf], qf, fzero, 0, 0, 0);
    #pragma unroll
    for(int nf = 0; nf < 2; ++nf){
      const float* bp = reinterpret_cast<const float*>(&bv[nf]);
      const float p0 = fmaf(st[nf][0], scale, bp[0]);
      const float p1 = fmaf(st[nf][1], scale, bp[1]);
      const float p2 = fmaf(st[nf][2], scale, bp[2]);
      const float p3 = fmaf(st[nf][3], scale, bp[3]);
      uint2 pw;
      pw.x = cvtpk(p0, p1);
      pw.y = cvtpk(p2, p3);
      *reinterpret_cast<uint2*>(Plb + (w*16 + col)*80 + nf*32 + g*8) = pw;
    }
    bf16x8 pa = *reinterpret_cast<const bf16x8*>(Plb + (w*16 + col)*80 + g*16);
    bf16x8 vfr[2];
    #pragma unroll
    for(int nf = 0; nf < 2; ++nf)
      vfr[nf] = *reinterpret_cast<const bf16x8*>(&Vt[nf*16 + col][ch*32 + g*8]);
    #pragma unroll
    for(int nf = 0; nf < 2; ++nf)
      oacc[nf] = __builtin_amdgcn_mfma_f32_16x16x32_bf16(pa, vfr[nf], oacc[nf], 0, 0, 0);
  }
  __syncthreads();   // all Kl reads done; safe to alias with Of
  #pragma unroll
  for(int nf = 0; nf < 2; ++nf)
    #pragma unroll
    for(int r = 0; r < 4; ++r)
      Of[w*16 + g*4 + r][nf*16 + col] = oacc[nf][r];
  __syncthreads();
  // epilogue: x1 = O + shortcut
  {
    const int tok = tid >> 2, q = tid & 3;
    const int hh = h0 + (tok >> 3), wp = w0 + (tok & 7);
    const size_t trow = tokbase + (size_t)hh*128 + wp;
    const size_t o = trow*(size_t)C + head*32 + q*8;
    float4 a0 = *reinterpret_cast<const float4*>(&Of[tok][q*8]);
    float4 a1 = *reinterpret_cast<const float4*>(&Of[tok][q*8 + 4]);
    const float4 x0 = *reinterpret_cast<const float4*>(x + o);
    const float4 x1 = *reinterpret_cast<const float4*>(x + o + 4);
    a0.x += x0.x; a0.y += x0.y; a0.z += x0.z; a0.w += x0.w;
    a1.x += x1.x; a1.y += x1.y; a1.z += x1.z; a1.w += x1.w;
    if(X1B){
      uint4 pk;
      pk.x = cvtpk(a0.x, a0.y);
      pk.y = cvtpk(a0.z, a0.w);
      pk.z = cvtpk(a1.x, a1.y);
      pk.w = cvtpk(a1.z, a1.w);
      *reinterpret_cast<uint4*>(x1b + o) = pk;
    }else{
      *reinterpret_cast<float4*>(out + o)     = a0;
      *reinterpret_cast<float4*>(out + o + 4) = a1;
    }
  }
}

// ---------------- LN2 + FC1 + GELU + FC2 + residual ----------------
// 32 tokens/block, 4096 blocks, 4 waves; single FC1->FC2 pass, 37KB LDS -> 4 blocks/CU.
template<bool X1B>
__global__ __launch_bounds__(256, 4)
void mlp_kernel(float* __restrict__ io,            // X1B ? out (write-only) : in-place x1/out
                const u16* __restrict__ x1b,       // X1B only
                const float* __restrict__ g2,
                const float* __restrict__ b2,
                const u16* __restrict__ w1P,
                const float* __restrict__ fb1,
                const u16* __restrict__ w2P,
                const float* __restrict__ fb2){
  __shared__ u16 xn[32][200];
  __shared__ u16 hl[32][392];
  const int tid = threadIdx.x;
  const size_t tok0 = (size_t)blockIdx.x * 32;
  {
    const int trow = tid >> 3;   // 0..31
    const int j = tid & 7;       // 24 floats each
    float v[24];
    if(X1B){
      const u16* xr = x1b + (tok0 + trow)*C + j*24;
      bf16x8 b0 = *reinterpret_cast<const bf16x8*>(xr);
      bf16x8 b1 = *reinterpret_cast<const bf16x8*>(xr + 8);
      bf16x8 b2_ = *reinterpret_cast<const bf16x8*>(xr + 16);
      #pragma unroll
      for(int e = 0; e < 8; ++e){ v[e] = bf2f((u16)b0[e]); v[8+e] = bf2f((u16)b1[e]); v[16+e] = bf2f((u16)b2_[e]); }
    }else{
      const float* xr = io + (tok0 + trow)*C + j*24;
      #pragma unroll
      for(int u = 0; u < 6; ++u){
        const float4 t = *reinterpret_cast<const float4*>(xr + u*4);
        v[u*4+0] = t.x; v[u*4+1] = t.y; v[u*4+2] = t.z; v[u*4+3] = t.w;
      }
    }
    float s1 = 0.f, s2 = 0.f;
    #pragma unroll
    for(int e = 0; e < 24; ++e){ s1 += v[e]; s2 += v[e]*v[e]; }
    s1 += __shfl_xor(s1, 1, 64); s2 += __shfl_xor(s2, 1, 64);
    s1 += __shfl_xor(s1, 2, 64); s2 += __shfl_xor(s2, 2, 64);
    s1 += __shfl_xor(s1, 4, 64); s2 += __shfl_xor(s2, 4, 64);
    const float mean = s1 * (1.f/192.f);
    const float rstd = rsqrtf(s2*(1.f/192.f) - mean*mean + 1e-5f);
    #pragma unroll
    for(int u = 0; u < 6; ++u){
      const float4 gv = *reinterpret_cast<const float4*>(g2 + j*24 + u*4);
      const float4 bv = *reinterpret_cast<const float4*>(b2 + j*24 + u*4);
      const float* gp = reinterpret_cast<const float*>(&gv);
      const float* bp = reinterpret_cast<const float*>(&bv);
      float c0 = (v[u*4+0] - mean)*rstd*gp[0] + bp[0];
      float c1 = (v[u*4+1] - mean)*rstd*gp[1] + bp[1];
      float c2 = (v[u*4+2] - mean)*rstd*gp[2] + bp[2];
      float c3 = (v[u*4+3] - mean)*rstd*gp[3] + bp[3];
      uint2 pk; pk.x = cvtpk(c0, c1); pk.y = cvtpk(c2, c3);
      *reinterpret_cast<uint2*>(&xn[trow][j*24 + u*4]) = pk;
    }
  }
  __syncthreads();
  const int lane = tid & 63, w = tid >> 6;   // w = 0..3
  const int g = lane >> 4, col = lane & 15;
  const f32x4 fzero = {0.f, 0.f, 0.f, 0.f};
  // ---- FC1: wave w -> hid cols [w*96, w*96+96) over all 32 rows; acc1[2][6] ----
  f32x4 acc1[2][6];
  #pragma unroll
  for(int mi = 0; mi < 2; ++mi)
    #pragma unroll
    for(int nf = 0; nf < 6; ++nf) acc1[mi][nf] = fzero;
  #pragma unroll
  for(int ks = 0; ks < 6; ++ks){
    bf16x8 wf[6];
    #pragma unroll
    for(int nf = 0; nf < 6; ++nf)
      wf[nf] = *reinterpret_cast<const bf16x8*>(w1P + ((size_t)(((w*6 + nf)*6 + ks)*64) + lane)*8);
    bf16x8 a[2];
    #pragma unroll
    for(int mi = 0; mi < 2; ++mi)
      a[mi] = *reinterpret_cast<const bf16x8*>(&xn[mi*16 + col][ks*32 + g*8]);
    #pragma unroll
    for(int nf = 0; nf < 6; ++nf)
      #pragma unroll
      for(int mi = 0; mi < 2; ++mi)
        acc1[mi][nf] = __builtin_amdgcn_mfma_f32_16x16x32_bf16(a[mi], wf[nf], acc1[mi][nf], 0, 0, 0);
  }
  // bias + gelu -> hl (consecutive-row pairs via cvt_pk)
  #pragma unroll
  for(int mi = 0; mi < 2; ++mi){
    #pragma unroll
    for(int nf = 0; nf < 6; ++nf){
      const int nl = w*96 + nf*16 + col;
      const float bb = fb1[nl];
      const int row0 = mi*16 + g*4;
      const unsigned p01 = cvtpk(gelu(acc1[mi][nf][0] + bb), gelu(acc1[mi][nf][1] + bb));
      const unsigned p23 = cvtpk(gelu(acc1[mi][nf][2] + bb), gelu(acc1[mi][nf][3] + bb));
      hl[row0 + 0][nl] = (u16)p01;
      hl[row0 + 1][nl] = (u16)(p01 >> 16);
      hl[row0 + 2][nl] = (u16)p23;
      hl[row0 + 3][nl] = (u16)(p23 >> 16);
    }
  }
  __syncthreads();   // hl ready; xn reads done
  // ---- FC2: wave w -> out cols [w*48, w*48+48) over all 32 rows; acc2[2][3], k = 384 ----
  f32x4 acc2[2][3];
  #pragma unroll
  for(int mi = 0; mi < 2; ++mi)
    #pragma unroll
    for(int nf = 0; nf < 3; ++nf) acc2[mi][nf] = fzero;
  #pragma unroll
  for(int ks = 0; ks < 12; ++ks){
    bf16x8 wf[3];
    #pragma unroll
    for(int nf = 0; nf < 3; ++nf)
      wf[nf] = *reinterpret_cast<const bf16x8*>(w2P + ((size_t)(((w*3 + nf)*12 + ks)*64) + lane)*8);
    bf16x8 a[2];
    #pragma unroll
    for(int mi = 0; mi < 2; ++mi)
      a[mi] = *reinterpret_cast<const bf16x8*>(&hl[mi*16 + col][ks*32 + g*8]);
    #pragma unroll
    for(int nf = 0; nf < 3; ++nf)
      #pragma unroll
      for(int mi = 0; mi < 2; ++mi)
        acc2[mi][nf] = __builtin_amdgcn_mfma_f32_16x16x32_bf16(a[mi], wf[nf], acc2[mi][nf], 0, 0, 0);
  }
  if(X1B){
    // stage mlp-out bf16 into xn (free after FC1), then pure vector write of x1 + mlp-out
    #pragma unroll
    for(int mi = 0; mi < 2; ++mi){
      #pragma unroll
      for(int nf = 0; nf < 3; ++nf){
        const int n = w*48 + nf*16 + col;
        const float bb = fb2[n];
        const int row0 = mi*16 + g*4;
        const unsigned p01 = cvtpk(acc2[mi][nf][0] + bb, acc2[mi][nf][1] + bb);
        const unsigned p23 = cvtpk(acc2[mi][nf][2] + bb, acc2[mi][nf][3] + bb);
        xn[row0 + 0][n] = (u16)p01;
        xn[row0 + 1][n] = (u16)(p01 >> 16);
        xn[row0 + 2][n] = (u16)p23;
        xn[row0 + 3][n] = (u16)(p23 >> 16);
      }
    }
    __syncthreads();
    const int trow = tid >> 3, j = tid & 7;
    const u16* xq = x1b + (tok0 + trow)*C + j*24;   // L2-hit (read by this block in LN)
    float* op = io + (tok0 + trow)*C + j*24;
    bf16x8 r0 = *reinterpret_cast<const bf16x8*>(xq);
    bf16x8 r1 = *reinterpret_cast<const bf16x8*>(xq + 8);
    bf16x8 r2 = *reinterpret_cast<const bf16x8*>(xq + 16);
    bf16x8 m0 = *reinterpret_cast<const bf16x8*>(&xn[trow][j*24]);
    bf16x8 m1 = *reinterpret_cast<const bf16x8*>(&xn[trow][j*24 + 8]);
    bf16x8 m2 = *reinterpret_cast<const bf16x8*>(&xn[trow][j*24 + 16]);
    float ov[24];
    #pragma unroll
    for(int e = 0; e < 8; ++e){
      ov[e]    = bf2f((u16)r0[e]) + bf2f((u16)m0[e]);
      ov[8+e]  = bf2f((u16)r1[e]) + bf2f((u16)m1[e]);
      ov[16+e] = bf2f((u16)r2[e]) + bf2f((u16)m2[e]);
    }
    #pragma unroll
    for(int u = 0; u < 6; ++u){
      float4 t; t.x = ov[u*4]; t.y = ov[u*4+1]; t.z = ov[u*4+2]; t.w = ov[u*4+3];
      *reinterpret_cast<float4*>(op + u*4) = t;
    }
  }else{
    // in-place scalar RMW
    #pragma unroll
    for(int mi = 0; mi < 2; ++mi){
      #pragma unroll
      for(int nf = 0; nf < 3; ++nf){
        const int n = w*48 + nf*16 + col;
        const float bb = fb2[n];
        #pragma unroll
        for(int r = 0; r < 4; ++r){
          const int row = mi*16 + g*4 + r;
          const size_t idx = (tok0 + row)*C + n;
          io[idx] = acc2[mi][nf][r] + bb + io[idx];
        }
      }
    }
  }
}

extern "C" void kernel_launch(void* const* d_in, const int* in_sizes, int n_in,
                              void* d_out, int out_size, void* d_ws, size_t ws_size,
                              hipStream_t stream){
  const float* x    = (const float*)d_in[0];
  const int*   rpi  = (const int*)  d_in[2];
  const float* n1g  = (const float*)d_in[3];
  const float* n1b  = (const float*)d_in[4];
  const float* qkvw = (const float*)d_in[5];
  const float* qkvb = (const float*)d_in[6];
  const float* rpb  = (const float*)d_in[7];
  const float* n2g  = (const float*)d_in[8];
  const float* n2b  = (const float*)d_in[9];
  const float* fc1w = (const float*)d_in[10];
  const float* fc1b = (const float*)d_in[11];
  const float* fc2w = (const float*)d_in[12];
  const float* fc2b = (const float*)d_in[13];
  float* out = (float*)d_out;
  char* ws = (char*)d_ws;
  u16*   qkvP    = (u16*)  (ws + 0);
  u16*   fc1P    = (u16*)  (ws + 221184);
  u16*   fc2P    = (u16*)  (ws + 368640);
  float* bias_pk = (float*)(ws + 516096);
  u16*   qkvbuf  = (u16*)  (ws + 1499136);       // 150994944 B
  u16*   x1b     = (u16*)  (ws + 152494080);     // 50331648 B (big-ws path only)
  if(ws_size < 152494080ull) return;
  const bool big = ws_size >= 202825728ull;
  prep_kernel<<<dim3(512), dim3(256), 0, stream>>>(qkvw, fc1w, fc2w, rpi, rpb, qkvP, fc1P, fc2P, bias_pk);
  qkv_kernel<<<dim3(4096), dim3(384), 0, stream>>>(x, n1g, n1b, qkvP, qkvb, qkvbuf);
  if(big){
    attn_kernel<true><<<dim3(2048, 6), dim3(256), 0, stream>>>(qkvbuf, bias_pk, x, out, x1b);
    mlp_kernel<true><<<dim3(4096), dim3(256), 0, stream>>>(out, x1b, n2g, n2b, fc1P, fc1b, fc2P, fc2b);
  }else{
    attn_kernel<false><<<dim3(2048, 6), dim3(256), 0, stream>>>(qkvbuf, bias_pk, x, out, nullptr);
    mlp_kernel<false><<<dim3(4096), dim3(256), 0, stream>>>(out, nullptr, n2g, n2b, fc1P, fc1b, fc2P, fc2b);
  }
}